// Round 3
// baseline (283.020 us; speedup 1.0000x reference)
//
#include <hip/hip_runtime.h>
#include <hip/hip_bf16.h>
#include <math.h>

// IntentionHeads R11 = R8 (129us best) + XCD swizzle + deep X prefetch.
//   R9 lesson: 64KB LDS / 256-reg blocks halve occupancy -> never.
//   R10 lesson: f32-in-LDS = 4x redundant per-wave cvt + 2x ds bytes; and
//     VGPR 64->84 crossed the 128 combined (V+A) boundary -> 3 waves/SIMD.
//     Confirmed win though: XCD swizzle halves FETCH (134->70MB).
// R11 changes vs R8 (register-neutral or better, numerics identical):
//   - T1 bijective XCD swizzle (grid 2048 % 8 == 0): head-pair blocks on
//     the same XCD -> partner's X reads hit L2 (~200cy vs ~900cy).
//   - Triple-buffered bf16 X staging: tile it+2 issued at TOP of iter it,
//     cvt+ds_write at BOTTOM of iter it+1 -> ~1.7 iter bodies of latency
//     cover (R8: ~0.7 same-iter). Costs +8 VGPR (second g set).
//   - B-frag prefetch dropped (-16 VGPR): bc loaded at iter top from
//     L2-hot Wc (512KB resident/XCD), ~200cy to first use ~= L2 latency.
//   - Net ~56 VGPR + 64 AGPR = 120 <= 128 -> 4 blocks/CU preserved.

#define TOKENS 65536
#define DIM    512
#define HID    256
#define ASTR   40    // X staging row stride in bf16 (32 + 8 pad, 16B mult)
#define ABUFB  5120  // one staging buffer: 64*ASTR*2 bytes
#define HSTR   264   // H row stride in bf16 (256 + 8 pad, 16B mult)

using short8 = __attribute__((ext_vector_type(8))) short;  // 8 x bf16
using f32x4  = __attribute__((ext_vector_type(4))) float;

// packed RNE f32->bf16 pair (v_perm byte-pack)
__device__ __forceinline__ unsigned int pkrne(float a, float b) {
    unsigned int ua = __float_as_uint(a);
    unsigned int ub = __float_as_uint(b);
    ua += 0x7FFFu + ((ua >> 16) & 1u);
    ub += 0x7FFFu + ((ub >> 16) & 1u);
    return __builtin_amdgcn_perm(ub, ua, 0x07060302u);  // [ua.hi16, ub.hi16]
}

__device__ __forceinline__ uint2 cvt4(f32x4 v) {
    return make_uint2(pkrne(v[0], v[1]), pkrne(v[2], v[3]));
}

__device__ __forceinline__ __hip_bfloat16 bf16rne(float x) {
    unsigned int u = __float_as_uint(x);
    u += 0x7FFFu + ((u >> 16) & 1u);
    unsigned short hs = (unsigned short)(u >> 16);
    return *(__hip_bfloat16*)&hs;
}

__device__ __forceinline__ float gelu_exact(float x) {
    // exact (erf) GELU, matches jax.nn.gelu(approximate=False)
    return 0.5f * x * (1.0f + erff(x * 0.7071067811865475f));
}

// ---------------- prep: weights f32 -> bf16 in workspace --------------------
// Wc  [512][512]: rows 0-255 vW1, 256-511 pW1
// W2c [32][256]:  rows 0-5 vW2, 6-15 zero, 16-17 pW2, 18-31 zero
__global__ __launch_bounds__(256)
void prep_kernel(const float* __restrict__ vW1, const float* __restrict__ pW1,
                 const float* __restrict__ vW2, const float* __restrict__ pW2,
                 __hip_bfloat16* __restrict__ Wc, __hip_bfloat16* __restrict__ W2c)
{
    const int i = blockIdx.x * 256 + threadIdx.x;   // f32x4 chunk index
    if (i < 65536) {                                // W1: 262144 elems
        const int flat = i * 4;
        f32x4 v = (flat < 131072) ? *(const f32x4*)(vW1 + flat)
                                  : *(const f32x4*)(pW1 + flat - 131072);
        *(uint2*)(Wc + flat) = cvt4(v);
    } else if (i < 65536 + 2048) {                  // W2c: 8192 elems
        const int flat = (i - 65536) * 4;
        const int row = flat >> 8, col = flat & 255;
        f32x4 v = (f32x4){0.f, 0.f, 0.f, 0.f};
        if (row < 6)                      v = *(const f32x4*)(vW2 + row * HID + col);
        else if (row >= 16 && row < 18)   v = *(const f32x4*)(pW2 + (row - 16) * HID + col);
        *(uint2*)(W2c + flat) = cvt4(v);
    }
}

// ---------------- main ------------------------------------------------------
__global__ __launch_bounds__(256, 3)
void intention_heads_kernel(const float* __restrict__ X,
                            const int* __restrict__ ids,
                            const __hip_bfloat16* __restrict__ Wc,
                            const __hip_bfloat16* __restrict__ W2c,
                            const float* __restrict__ vb1,
                            const float* __restrict__ pb1,
                            const float* __restrict__ vb2,
                            const float* __restrict__ pb2,
                            float* __restrict__ out)
{
    // LDS union: X staging A0/A1/A2 (3 x 64x40 bf16 = 15.4KB) then H
    // 64x264 bf16 (33.8KB). 33792 B -> 4 blocks/CU.
    __shared__ __align__(16) unsigned char smem[64 * HSTR * 2];
    __hip_bfloat16* H = (__hip_bfloat16*)smem;

    // T1 bijective XCD swizzle (2048 % 8 == 0): head pair (2t,2t+1) and
    // neighboring token tiles land on one XCD -> X shared in its L2.
    const int cpx = gridDim.x >> 3;
    const int bid = (blockIdx.x & 7) * cpx + (blockIdx.x >> 3);

    const int head = bid & 1;           // 0 = vehicle, 1 = pedestrian
    const int row0 = (bid >> 1) * 64;

    const int tid  = threadIdx.x;
    const int wave = tid >> 6;          // 0..3 -> hidden cols wave*64
    const int lane = tid & 63;
    const int quad = lane >> 4;
    const int l16  = lane & 15;
    const int wcol = wave * 64;

    // X staging: thread owns f32x4 at col q*4 of rows r2 and r2+32
    const int q  = tid & 7;
    const int r2 = tid >> 3;            // 0..31
    const float* Xs = X + (long)(row0 + r2) * DIM + q * 4;

    // B-frag row pointers (bf16 weights, row-major [n][k])
    const __hip_bfloat16* Wrow[4];
    #pragma unroll
    for (int j = 0; j < 4; ++j)
        Wrow[j] = Wc + (long)(head * 256 + wcol + j * 16 + l16) * DIM + quad * 8;

    f32x4 acc[4][4];
    #pragma unroll
    for (int i = 0; i < 4; ++i)
        #pragma unroll
        for (int j = 0; j < 4; ++j)
            acc[i][j] = (f32x4){0.f, 0.f, 0.f, 0.f};

    // ---- prologue: load tiles 0,1 raw; stage tile 0; rotate ----
    f32x4 ga0 = *(const f32x4*)(Xs);
    f32x4 ga1 = *(const f32x4*)(Xs + 32 * DIM);
    f32x4 gb0 = *(const f32x4*)(Xs + 32);
    f32x4 gb1 = *(const f32x4*)(Xs + 32 * DIM + 32);
    {
        __hip_bfloat16* A = (__hip_bfloat16*)smem;   // buffer 0
        *(uint2*)&A[r2 * ASTR + q * 4]        = cvt4(ga0);
        *(uint2*)&A[(r2 + 32) * ASTR + q * 4] = cvt4(ga1);
    }
    __syncthreads();
    ga0 = gb0; ga1 = gb1;               // ga now holds tile 1 raw

    // ---- K loop: 16 iters, BK=32, triple buffer, deep prefetch ----
    // entering iter it: buf[it%3] holds tile it (bf16); ga holds tile it+1
    // raw (issued ~1.7 iters ago); bottom of iter converts ga into
    // buf[(it+1)%3]; top of iter issues tile it+2 into gb.
    #pragma unroll
    for (int it = 0; it < DIM / 32; ++it) {
        __hip_bfloat16* cur = (__hip_bfloat16*)(smem + (it % 3) * ABUFB);
        __hip_bfloat16* nxt = (__hip_bfloat16*)(smem + ((it + 1) % 3) * ABUFB);

        // issue tile it+2 raw loads (consumed bottom of iter it+1)
        if (it < 14) {
            gb0 = *(const f32x4*)(Xs + (it + 2) * 32);
            gb1 = *(const f32x4*)(Xs + 32 * DIM + (it + 2) * 32);
        }

        // this iter's B frags from L2-hot Wc (~200cy to first MFMA use)
        short8 bc[4];
        #pragma unroll
        for (int j = 0; j < 4; ++j)
            bc[j] = *(const short8*)(Wrow[j] + it * 32);

        short8 af[4];
        #pragma unroll
        for (int i = 0; i < 4; ++i)
            af[i] = *(const short8*)&cur[(i * 16 + l16) * ASTR + quad * 8];

        #pragma unroll
        for (int i = 0; i < 4; ++i)
            #pragma unroll
            for (int j = 0; j < 4; ++j)
                acc[i][j] = __builtin_amdgcn_mfma_f32_16x16x32_bf16(af[i], bc[j], acc[i][j], 0, 0, 0);

        // convert+stage tile it+1 (raw data in flight since iter it-1 top)
        if (it < 15) {
            *(uint2*)&nxt[r2 * ASTR + q * 4]        = cvt4(ga0);
            *(uint2*)&nxt[(r2 + 32) * ASTR + q * 4] = cvt4(ga1);
        }
        __syncthreads();
        ga0 = gb0; ga1 = gb1;
    }

    // ------------- bias + GELU, stage H tile (bf16) -----------------------
    const float* b1 = head ? pb1 : vb1;
    float b1v[4];
    #pragma unroll
    for (int j = 0; j < 4; ++j)
        b1v[j] = b1[wcol + j * 16 + l16];

    #pragma unroll
    for (int i = 0; i < 4; ++i) {
        #pragma unroll
        for (int j = 0; j < 4; ++j) {
            const int col = wcol + j * 16 + l16;
            #pragma unroll
            for (int rr = 0; rr < 4; ++rr) {
                const int row = i * 16 + quad * 4 + rr;
                H[row * HSTR + col] = bf16rne(gelu_exact(acc[i][j][rr] + b1v[j]));
            }
        }
    }
    __syncthreads();

    // ------------- layer 2: H[64x256] @ W2^T (zero-padded to 16) ----------
    const float* b2 = head ? pb2 : vb2;
    const int nOut = head ? 2 : 6;

    f32x4 acc2 = (f32x4){0.f, 0.f, 0.f, 0.f};
    const int tokb = wave * 16;
    const short* hbase  = (const short*)&H[(tokb + l16) * HSTR + quad * 8];
    const __hip_bfloat16* w2base = W2c + (head * 16 + l16) * HID + quad * 8;
    #pragma unroll
    for (int k0 = 0; k0 < HID; k0 += 32) {
        short8 af    = *(const short8*)(hbase + k0);
        short8 bfrag = *(const short8*)(w2base + k0);   // zero rows pad n>=nOut
        acc2 = __builtin_amdgcn_mfma_f32_16x16x32_bf16(af, bfrag, acc2, 0, 0, 0);
    }

    // ------------- masked epilogue (f32 writes) ---------------------------
    const float b2v = (l16 < nOut) ? b2[l16] : 0.0f;

    #pragma unroll
    for (int rr = 0; rr < 4; ++rr) {
        const int t = row0 + tokb + quad * 4 + rr;
        const int type = ids[t];
        if (head == 0) {
            if (l16 == 0) {
                out[TOKENS * 6 + t] = (type == 1) ? 1.0f : 0.0f;
                out[TOKENS * 7 + t] = (type == 2) ? 1.0f : 0.0f;
            }
            if (l16 < 6) {
                if (type == 1)
                    out[t * 6 + l16] = acc2[rr] + b2v;
                else if (type != 2)
                    out[t * 6 + l16] = 0.0f;        // types 0,3 -> zeros
                // type==2 slots written by the pedestrian block
            }
        } else {
            if (l16 < 6 && type == 2)
                out[t * 6 + l16] = (l16 < 2) ? (acc2[rr] + b2v) : 0.0f;
        }
    }
}

extern "C" void kernel_launch(void* const* d_in, const int* in_sizes, int n_in,
                              void* d_out, int out_size, void* d_ws, size_t ws_size,
                              hipStream_t stream) {
    (void)n_in; (void)out_size; (void)ws_size;
    const float* X   = (const float*)d_in[0];
    const int*   ids = (const int*)d_in[1];
    const float* vW1 = (const float*)d_in[2];
    const float* vb1 = (const float*)d_in[3];
    const float* vW2 = (const float*)d_in[4];
    const float* vb2 = (const float*)d_in[5];
    const float* pW1 = (const float*)d_in[6];
    const float* pb1 = (const float*)d_in[7];
    const float* pW2 = (const float*)d_in[8];
    const float* pb2 = (const float*)d_in[9];
    float* out = (float*)d_out;

    // workspace: Wc [512*512] bf16 (512KB) ++ W2c [32*256] bf16 (16KB)
    __hip_bfloat16* Wc  = (__hip_bfloat16*)d_ws;
    __hip_bfloat16* W2c = Wc + 512 * DIM;

    hipLaunchKernelGGL(prep_kernel, dim3(264), dim3(256), 0, stream,
                       vW1, pW1, vW2, pW2, Wc, W2c);

    const int tokens = in_sizes[1];            // 65536
    const int grid   = (tokens / 64) * 2;      // token-tile x head

    hipLaunchKernelGGL(intention_heads_kernel, dim3(grid), dim3(256), 0, stream,
                       X, ids, Wc, W2c, vb1, pb1, vb2, pb2, out);
}

// Round 4
// 282.485 us; speedup vs baseline: 1.0019x; 1.0019x over previous
//
#include <hip/hip_runtime.h>
#include <hip/hip_bf16.h>
#include <math.h>

// IntentionHeads R12 = R11 + counted barriers (no vmcnt drain).
//   Evidence ladder: R8=R11=130us despite prefetch-depth/FETCH/B-timing
//   changes; R10 showed occupancy 4->3 blocks = +47% time. All pipes <40%.
//   Diagnosis (matches learn_hip m233 2-phase pathology): __syncthreads
//   emits s_waitcnt vmcnt(0) lgkmcnt(0) before s_barrier, force-draining
//   the X prefetch issued earlier the same iter -> effective prefetch
//   depth collapses to ~1 iter body in every variant -> identical times.
// R12 change (single variable):
//   - ALL global loads here land in REGISTERS (X prefetch, B frags), so
//     vmcnt flight is never cross-wave-visible. Barrier only needs the
//     ds_writes ordered -> lgkmcnt(0). Replace __syncthreads with
//     { sched_barrier; s_waitcnt lgkmcnt(0); s_barrier; sched_barrier }.
//     X loads (issued 2 iters ahead) and B loads now genuinely stay in
//     flight across barriers (T4 counted-wait mechanism, m218).
//   - Everything else identical to R11: 2048 blocks, 4 blk/CU, 64+64 regs,
//     triple-buffer bf16 staging, XCD swizzle, same numerics/op order.

#define TOKENS 65536
#define DIM    512
#define HID    256
#define ASTR   40    // X staging row stride in bf16 (32 + 8 pad, 16B mult)
#define ABUFB  5120  // one staging buffer: 64*ASTR*2 bytes
#define HSTR   264   // H row stride in bf16 (256 + 8 pad, 16B mult)

using short8 = __attribute__((ext_vector_type(8))) short;  // 8 x bf16
using f32x4  = __attribute__((ext_vector_type(4))) float;

// lgkm-only barrier: LDS producer/consumer ordering WITHOUT draining vmcnt.
// Safe here because no global->LDS traffic exists (global loads are
// register-only); ds_writes are fenced by lgkmcnt(0). sched_barrier(0)
// pins LDS ops on the correct side (rule #18 analog).
#define BAR()                                                      \
    do {                                                           \
        __builtin_amdgcn_sched_barrier(0);                         \
        asm volatile("s_waitcnt lgkmcnt(0)" ::: "memory");         \
        __builtin_amdgcn_s_barrier();                              \
        __builtin_amdgcn_sched_barrier(0);                         \
    } while (0)

// packed RNE f32->bf16 pair (v_perm byte-pack)
__device__ __forceinline__ unsigned int pkrne(float a, float b) {
    unsigned int ua = __float_as_uint(a);
    unsigned int ub = __float_as_uint(b);
    ua += 0x7FFFu + ((ua >> 16) & 1u);
    ub += 0x7FFFu + ((ub >> 16) & 1u);
    return __builtin_amdgcn_perm(ub, ua, 0x07060302u);  // [ua.hi16, ub.hi16]
}

__device__ __forceinline__ uint2 cvt4(f32x4 v) {
    return make_uint2(pkrne(v[0], v[1]), pkrne(v[2], v[3]));
}

__device__ __forceinline__ __hip_bfloat16 bf16rne(float x) {
    unsigned int u = __float_as_uint(x);
    u += 0x7FFFu + ((u >> 16) & 1u);
    unsigned short hs = (unsigned short)(u >> 16);
    return *(__hip_bfloat16*)&hs;
}

__device__ __forceinline__ float gelu_exact(float x) {
    // exact (erf) GELU, matches jax.nn.gelu(approximate=False)
    return 0.5f * x * (1.0f + erff(x * 0.7071067811865475f));
}

// ---------------- prep: weights f32 -> bf16 in workspace --------------------
// Wc  [512][512]: rows 0-255 vW1, 256-511 pW1
// W2c [32][256]:  rows 0-5 vW2, 6-15 zero, 16-17 pW2, 18-31 zero
__global__ __launch_bounds__(256)
void prep_kernel(const float* __restrict__ vW1, const float* __restrict__ pW1,
                 const float* __restrict__ vW2, const float* __restrict__ pW2,
                 __hip_bfloat16* __restrict__ Wc, __hip_bfloat16* __restrict__ W2c)
{
    const int i = blockIdx.x * 256 + threadIdx.x;   // f32x4 chunk index
    if (i < 65536) {                                // W1: 262144 elems
        const int flat = i * 4;
        f32x4 v = (flat < 131072) ? *(const f32x4*)(vW1 + flat)
                                  : *(const f32x4*)(pW1 + flat - 131072);
        *(uint2*)(Wc + flat) = cvt4(v);
    } else if (i < 65536 + 2048) {                  // W2c: 8192 elems
        const int flat = (i - 65536) * 4;
        const int row = flat >> 8, col = flat & 255;
        f32x4 v = (f32x4){0.f, 0.f, 0.f, 0.f};
        if (row < 6)                      v = *(const f32x4*)(vW2 + row * HID + col);
        else if (row >= 16 && row < 18)   v = *(const f32x4*)(pW2 + (row - 16) * HID + col);
        *(uint2*)(W2c + flat) = cvt4(v);
    }
}

// ---------------- main ------------------------------------------------------
__global__ __launch_bounds__(256, 3)
void intention_heads_kernel(const float* __restrict__ X,
                            const int* __restrict__ ids,
                            const __hip_bfloat16* __restrict__ Wc,
                            const __hip_bfloat16* __restrict__ W2c,
                            const float* __restrict__ vb1,
                            const float* __restrict__ pb1,
                            const float* __restrict__ vb2,
                            const float* __restrict__ pb2,
                            float* __restrict__ out)
{
    // LDS union: X staging A0/A1/A2 (3 x 64x40 bf16 = 15.4KB) then H
    // 64x264 bf16 (33.8KB). 33792 B -> 4 blocks/CU.
    __shared__ __align__(16) unsigned char smem[64 * HSTR * 2];
    __hip_bfloat16* H = (__hip_bfloat16*)smem;

    // T1 bijective XCD swizzle (2048 % 8 == 0): head pair (2t,2t+1) and
    // neighboring token tiles land on one XCD -> X shared in its L2.
    const int cpx = gridDim.x >> 3;
    const int bid = (blockIdx.x & 7) * cpx + (blockIdx.x >> 3);

    const int head = bid & 1;           // 0 = vehicle, 1 = pedestrian
    const int row0 = (bid >> 1) * 64;

    const int tid  = threadIdx.x;
    const int wave = tid >> 6;          // 0..3 -> hidden cols wave*64
    const int lane = tid & 63;
    const int quad = lane >> 4;
    const int l16  = lane & 15;
    const int wcol = wave * 64;

    // X staging: thread owns f32x4 at col q*4 of rows r2 and r2+32
    const int q  = tid & 7;
    const int r2 = tid >> 3;            // 0..31
    const float* Xs = X + (long)(row0 + r2) * DIM + q * 4;

    // B-frag row pointers (bf16 weights, row-major [n][k])
    const __hip_bfloat16* Wrow[4];
    #pragma unroll
    for (int j = 0; j < 4; ++j)
        Wrow[j] = Wc + (long)(head * 256 + wcol + j * 16 + l16) * DIM + quad * 8;

    f32x4 acc[4][4];
    #pragma unroll
    for (int i = 0; i < 4; ++i)
        #pragma unroll
        for (int j = 0; j < 4; ++j)
            acc[i][j] = (f32x4){0.f, 0.f, 0.f, 0.f};

    // ---- prologue: load tiles 0,1 raw; stage tile 0; rotate ----
    f32x4 ga0 = *(const f32x4*)(Xs);
    f32x4 ga1 = *(const f32x4*)(Xs + 32 * DIM);
    f32x4 gb0 = *(const f32x4*)(Xs + 32);
    f32x4 gb1 = *(const f32x4*)(Xs + 32 * DIM + 32);
    {
        __hip_bfloat16* A = (__hip_bfloat16*)smem;   // buffer 0
        *(uint2*)&A[r2 * ASTR + q * 4]        = cvt4(ga0);
        *(uint2*)&A[(r2 + 32) * ASTR + q * 4] = cvt4(ga1);
    }
    BAR();
    ga0 = gb0; ga1 = gb1;               // ga now holds tile 1 raw

    // ---- K loop: 16 iters, BK=32, triple buffer, deep prefetch ----
    // entering iter it: buf[it%3] holds tile it (bf16); ga holds tile it+1
    // raw (issued ~1.7 iters ago, still in flight across barriers); bottom
    // of iter converts ga into buf[(it+1)%3]; top issues tile it+2 into gb.
    #pragma unroll
    for (int it = 0; it < DIM / 32; ++it) {
        __hip_bfloat16* cur = (__hip_bfloat16*)(smem + (it % 3) * ABUFB);
        __hip_bfloat16* nxt = (__hip_bfloat16*)(smem + ((it + 1) % 3) * ABUFB);

        // issue tile it+2 raw loads (consumed bottom of iter it+1)
        if (it < 14) {
            gb0 = *(const f32x4*)(Xs + (it + 2) * 32);
            gb1 = *(const f32x4*)(Xs + 32 * DIM + (it + 2) * 32);
        }

        // this iter's B frags from L2-hot Wc
        short8 bc[4];
        #pragma unroll
        for (int j = 0; j < 4; ++j)
            bc[j] = *(const short8*)(Wrow[j] + it * 32);

        short8 af[4];
        #pragma unroll
        for (int i = 0; i < 4; ++i)
            af[i] = *(const short8*)&cur[(i * 16 + l16) * ASTR + quad * 8];

        #pragma unroll
        for (int i = 0; i < 4; ++i)
            #pragma unroll
            for (int j = 0; j < 4; ++j)
                acc[i][j] = __builtin_amdgcn_mfma_f32_16x16x32_bf16(af[i], bc[j], acc[i][j], 0, 0, 0);

        // convert+stage tile it+1 (raw data in flight since iter it-1 top)
        if (it < 15) {
            *(uint2*)&nxt[r2 * ASTR + q * 4]        = cvt4(ga0);
            *(uint2*)&nxt[(r2 + 32) * ASTR + q * 4] = cvt4(ga1);
        }
        BAR();
        ga0 = gb0; ga1 = gb1;
    }

    // ------------- bias + GELU, stage H tile (bf16) -----------------------
    const float* b1 = head ? pb1 : vb1;
    float b1v[4];
    #pragma unroll
    for (int j = 0; j < 4; ++j)
        b1v[j] = b1[wcol + j * 16 + l16];

    #pragma unroll
    for (int i = 0; i < 4; ++i) {
        #pragma unroll
        for (int j = 0; j < 4; ++j) {
            const int col = wcol + j * 16 + l16;
            #pragma unroll
            for (int rr = 0; rr < 4; ++rr) {
                const int row = i * 16 + quad * 4 + rr;
                H[row * HSTR + col] = bf16rne(gelu_exact(acc[i][j][rr] + b1v[j]));
            }
        }
    }
    BAR();

    // ------------- layer 2: H[64x256] @ W2^T (zero-padded to 16) ----------
    const float* b2 = head ? pb2 : vb2;
    const int nOut = head ? 2 : 6;

    f32x4 acc2 = (f32x4){0.f, 0.f, 0.f, 0.f};
    const int tokb = wave * 16;
    const short* hbase  = (const short*)&H[(tokb + l16) * HSTR + quad * 8];
    const __hip_bfloat16* w2base = W2c + (head * 16 + l16) * HID + quad * 8;
    #pragma unroll
    for (int k0 = 0; k0 < HID; k0 += 32) {
        short8 af    = *(const short8*)(hbase + k0);
        short8 bfrag = *(const short8*)(w2base + k0);   // zero rows pad n>=nOut
        acc2 = __builtin_amdgcn_mfma_f32_16x16x32_bf16(af, bfrag, acc2, 0, 0, 0);
    }

    // ------------- masked epilogue (f32 writes) ---------------------------
    const float b2v = (l16 < nOut) ? b2[l16] : 0.0f;

    #pragma unroll
    for (int rr = 0; rr < 4; ++rr) {
        const int t = row0 + tokb + quad * 4 + rr;
        const int type = ids[t];
        if (head == 0) {
            if (l16 == 0) {
                out[TOKENS * 6 + t] = (type == 1) ? 1.0f : 0.0f;
                out[TOKENS * 7 + t] = (type == 2) ? 1.0f : 0.0f;
            }
            if (l16 < 6) {
                if (type == 1)
                    out[t * 6 + l16] = acc2[rr] + b2v;
                else if (type != 2)
                    out[t * 6 + l16] = 0.0f;        // types 0,3 -> zeros
                // type==2 slots written by the pedestrian block
            }
        } else {
            if (l16 < 6 && type == 2)
                out[t * 6 + l16] = (l16 < 2) ? (acc2[rr] + b2v) : 0.0f;
        }
    }
}

extern "C" void kernel_launch(void* const* d_in, const int* in_sizes, int n_in,
                              void* d_out, int out_size, void* d_ws, size_t ws_size,
                              hipStream_t stream) {
    (void)n_in; (void)out_size; (void)ws_size;
    const float* X   = (const float*)d_in[0];
    const int*   ids = (const int*)d_in[1];
    const float* vW1 = (const float*)d_in[2];
    const float* vb1 = (const float*)d_in[3];
    const float* vW2 = (const float*)d_in[4];
    const float* vb2 = (const float*)d_in[5];
    const float* pW1 = (const float*)d_in[6];
    const float* pb1 = (const float*)d_in[7];
    const float* pW2 = (const float*)d_in[8];
    const float* pb2 = (const float*)d_in[9];
    float* out = (float*)d_out;

    // workspace: Wc [512*512] bf16 (512KB) ++ W2c [32*256] bf16 (16KB)
    __hip_bfloat16* Wc  = (__hip_bfloat16*)d_ws;
    __hip_bfloat16* W2c = Wc + 512 * DIM;

    hipLaunchKernelGGL(prep_kernel, dim3(264), dim3(256), 0, stream,
                       vW1, pW1, vW2, pW2, Wc, W2c);

    const int tokens = in_sizes[1];            // 65536
    const int grid   = (tokens / 64) * 2;      // token-tile x head

    hipLaunchKernelGGL(intention_heads_kernel, dim3(grid), dim3(256), 0, stream,
                       X, ids, Wc, W2c, vb1, pb1, vb2, pb2, out);
}

// Round 5
// 275.706 us; speedup vs baseline: 1.0265x; 1.0246x over previous
//
#include <hip/hip_runtime.h>
#include <hip/hip_bf16.h>
#include <math.h>

// IntentionHeads R13 = R12 + branch-free fast erf (A&S 7.1.26).
//   R8=R11=R12=130us across prefetch-depth / barrier-semantics / FETCH
//   changes -> K-loop memory theories exonerated. Counter-as-clock:
//   VALUBusy 34% = ~102k cy/SIMD; only inventory that reproduces it is
//   libm erff (divergent multi-range, ~100 slots) x 64 evals/thread
//   => GELU is a serial VALU window of ~40us of the 130us.
// R13 change (single variable):
//   - gelu_exact now uses Abramowitz-Stegun 7.1.26 erf: branch-free,
//     ~15 VALU (v_rcp + 5 fma + hw v_exp_f32 + copysign), |err|<=1.5e-7
//     -- 2-3 orders below one bf16 ulp of H, so H bits unchanged and
//     absmax must remain exactly 0.015625.
//   - Everything else identical to R12 (2048 blocks, 4 blk/CU, 64+64
//     regs, triple-buffer staging, XCD swizzle, lgkm-only barriers).

#define TOKENS 65536
#define DIM    512
#define HID    256
#define ASTR   40    // X staging row stride in bf16 (32 + 8 pad, 16B mult)
#define ABUFB  5120  // one staging buffer: 64*ASTR*2 bytes
#define HSTR   264   // H row stride in bf16 (256 + 8 pad, 16B mult)

using short8 = __attribute__((ext_vector_type(8))) short;  // 8 x bf16
using f32x4  = __attribute__((ext_vector_type(4))) float;

// lgkm-only barrier: LDS producer/consumer ordering WITHOUT draining vmcnt.
// Safe here because no global->LDS traffic exists (global loads are
// register-only); ds_writes are fenced by lgkmcnt(0).
#define BAR()                                                      \
    do {                                                           \
        __builtin_amdgcn_sched_barrier(0);                         \
        asm volatile("s_waitcnt lgkmcnt(0)" ::: "memory");         \
        __builtin_amdgcn_s_barrier();                              \
        __builtin_amdgcn_sched_barrier(0);                         \
    } while (0)

// packed RNE f32->bf16 pair (v_perm byte-pack)
__device__ __forceinline__ unsigned int pkrne(float a, float b) {
    unsigned int ua = __float_as_uint(a);
    unsigned int ub = __float_as_uint(b);
    ua += 0x7FFFu + ((ua >> 16) & 1u);
    ub += 0x7FFFu + ((ub >> 16) & 1u);
    return __builtin_amdgcn_perm(ub, ua, 0x07060302u);  // [ua.hi16, ub.hi16]
}

__device__ __forceinline__ uint2 cvt4(f32x4 v) {
    return make_uint2(pkrne(v[0], v[1]), pkrne(v[2], v[3]));
}

__device__ __forceinline__ __hip_bfloat16 bf16rne(float x) {
    unsigned int u = __float_as_uint(x);
    u += 0x7FFFu + ((u >> 16) & 1u);
    unsigned short hs = (unsigned short)(u >> 16);
    return *(__hip_bfloat16*)&hs;
}

__device__ __forceinline__ float gelu_exact(float x) {
    // exact-GELU via branch-free A&S 7.1.26 erf, |abs err| <= 1.5e-7:
    //   erf(z) = 1 - (a1 t + .. + a5 t^5) e^{-z^2},  t = 1/(1+0.3275911 z)
    // Replaces divergent ~100-slot libm erff (R12 PMC: VALUBusy 34% ~ GELU).
    // Error is far below one bf16 ulp of H -> output bits unchanged.
    const float z  = fabsf(x) * 0.7071067811865475f;
    const float t  = __builtin_amdgcn_rcpf(fmaf(0.3275911f, z, 1.0f));
    float p = fmaf(1.061405429f, t, -1.453152027f);
    p = fmaf(p, t, 1.421413741f);
    p = fmaf(p, t, -0.284496736f);
    p = fmaf(p, t, 0.254829592f);
    p = p * t;
    const float e  = __expf(-z * z);           // v_exp_f32 path
    const float er = fmaf(-p, e, 1.0f);        // erf(|z|) >= 0
    return 0.5f * x * (1.0f + copysignf(er, x));
}

// ---------------- prep: weights f32 -> bf16 in workspace --------------------
// Wc  [512][512]: rows 0-255 vW1, 256-511 pW1
// W2c [32][256]:  rows 0-5 vW2, 6-15 zero, 16-17 pW2, 18-31 zero
__global__ __launch_bounds__(256)
void prep_kernel(const float* __restrict__ vW1, const float* __restrict__ pW1,
                 const float* __restrict__ vW2, const float* __restrict__ pW2,
                 __hip_bfloat16* __restrict__ Wc, __hip_bfloat16* __restrict__ W2c)
{
    const int i = blockIdx.x * 256 + threadIdx.x;   // f32x4 chunk index
    if (i < 65536) {                                // W1: 262144 elems
        const int flat = i * 4;
        f32x4 v = (flat < 131072) ? *(const f32x4*)(vW1 + flat)
                                  : *(const f32x4*)(pW1 + flat - 131072);
        *(uint2*)(Wc + flat) = cvt4(v);
    } else if (i < 65536 + 2048) {                  // W2c: 8192 elems
        const int flat = (i - 65536) * 4;
        const int row = flat >> 8, col = flat & 255;
        f32x4 v = (f32x4){0.f, 0.f, 0.f, 0.f};
        if (row < 6)                      v = *(const f32x4*)(vW2 + row * HID + col);
        else if (row >= 16 && row < 18)   v = *(const f32x4*)(pW2 + (row - 16) * HID + col);
        *(uint2*)(W2c + flat) = cvt4(v);
    }
}

// ---------------- main ------------------------------------------------------
__global__ __launch_bounds__(256, 3)
void intention_heads_kernel(const float* __restrict__ X,
                            const int* __restrict__ ids,
                            const __hip_bfloat16* __restrict__ Wc,
                            const __hip_bfloat16* __restrict__ W2c,
                            const float* __restrict__ vb1,
                            const float* __restrict__ pb1,
                            const float* __restrict__ vb2,
                            const float* __restrict__ pb2,
                            float* __restrict__ out)
{
    // LDS union: X staging A0/A1/A2 (3 x 64x40 bf16 = 15.4KB) then H
    // 64x264 bf16 (33.8KB). 33792 B -> 4 blocks/CU.
    __shared__ __align__(16) unsigned char smem[64 * HSTR * 2];
    __hip_bfloat16* H = (__hip_bfloat16*)smem;

    // T1 bijective XCD swizzle (2048 % 8 == 0): head pair (2t,2t+1) and
    // neighboring token tiles land on one XCD -> X shared in its L2.
    const int cpx = gridDim.x >> 3;
    const int bid = (blockIdx.x & 7) * cpx + (blockIdx.x >> 3);

    const int head = bid & 1;           // 0 = vehicle, 1 = pedestrian
    const int row0 = (bid >> 1) * 64;

    const int tid  = threadIdx.x;
    const int wave = tid >> 6;          // 0..3 -> hidden cols wave*64
    const int lane = tid & 63;
    const int quad = lane >> 4;
    const int l16  = lane & 15;
    const int wcol = wave * 64;

    // X staging: thread owns f32x4 at col q*4 of rows r2 and r2+32
    const int q  = tid & 7;
    const int r2 = tid >> 3;            // 0..31
    const float* Xs = X + (long)(row0 + r2) * DIM + q * 4;

    // B-frag row pointers (bf16 weights, row-major [n][k])
    const __hip_bfloat16* Wrow[4];
    #pragma unroll
    for (int j = 0; j < 4; ++j)
        Wrow[j] = Wc + (long)(head * 256 + wcol + j * 16 + l16) * DIM + quad * 8;

    f32x4 acc[4][4];
    #pragma unroll
    for (int i = 0; i < 4; ++i)
        #pragma unroll
        for (int j = 0; j < 4; ++j)
            acc[i][j] = (f32x4){0.f, 0.f, 0.f, 0.f};

    // ---- prologue: load tiles 0,1 raw; stage tile 0; rotate ----
    f32x4 ga0 = *(const f32x4*)(Xs);
    f32x4 ga1 = *(const f32x4*)(Xs + 32 * DIM);
    f32x4 gb0 = *(const f32x4*)(Xs + 32);
    f32x4 gb1 = *(const f32x4*)(Xs + 32 * DIM + 32);
    {
        __hip_bfloat16* A = (__hip_bfloat16*)smem;   // buffer 0
        *(uint2*)&A[r2 * ASTR + q * 4]        = cvt4(ga0);
        *(uint2*)&A[(r2 + 32) * ASTR + q * 4] = cvt4(ga1);
    }
    BAR();
    ga0 = gb0; ga1 = gb1;               // ga now holds tile 1 raw

    // ---- K loop: 16 iters, BK=32, triple buffer, deep prefetch ----
    // entering iter it: buf[it%3] holds tile it (bf16); ga holds tile it+1
    // raw (issued ~1.7 iters ago, still in flight across barriers); bottom
    // of iter converts ga into buf[(it+1)%3]; top issues tile it+2 into gb.
    #pragma unroll
    for (int it = 0; it < DIM / 32; ++it) {
        __hip_bfloat16* cur = (__hip_bfloat16*)(smem + (it % 3) * ABUFB);
        __hip_bfloat16* nxt = (__hip_bfloat16*)(smem + ((it + 1) % 3) * ABUFB);

        // issue tile it+2 raw loads (consumed bottom of iter it+1)
        if (it < 14) {
            gb0 = *(const f32x4*)(Xs + (it + 2) * 32);
            gb1 = *(const f32x4*)(Xs + 32 * DIM + (it + 2) * 32);
        }

        // this iter's B frags from L2-hot Wc
        short8 bc[4];
        #pragma unroll
        for (int j = 0; j < 4; ++j)
            bc[j] = *(const short8*)(Wrow[j] + it * 32);

        short8 af[4];
        #pragma unroll
        for (int i = 0; i < 4; ++i)
            af[i] = *(const short8*)&cur[(i * 16 + l16) * ASTR + quad * 8];

        #pragma unroll
        for (int i = 0; i < 4; ++i)
            #pragma unroll
            for (int j = 0; j < 4; ++j)
                acc[i][j] = __builtin_amdgcn_mfma_f32_16x16x32_bf16(af[i], bc[j], acc[i][j], 0, 0, 0);

        // convert+stage tile it+1 (raw data in flight since iter it-1 top)
        if (it < 15) {
            *(uint2*)&nxt[r2 * ASTR + q * 4]        = cvt4(ga0);
            *(uint2*)&nxt[(r2 + 32) * ASTR + q * 4] = cvt4(ga1);
        }
        BAR();
        ga0 = gb0; ga1 = gb1;
    }

    // ------------- bias + GELU, stage H tile (bf16) -----------------------
    const float* b1 = head ? pb1 : vb1;
    float b1v[4];
    #pragma unroll
    for (int j = 0; j < 4; ++j)
        b1v[j] = b1[wcol + j * 16 + l16];

    #pragma unroll
    for (int i = 0; i < 4; ++i) {
        #pragma unroll
        for (int j = 0; j < 4; ++j) {
            const int col = wcol + j * 16 + l16;
            #pragma unroll
            for (int rr = 0; rr < 4; ++rr) {
                const int row = i * 16 + quad * 4 + rr;
                H[row * HSTR + col] = bf16rne(gelu_exact(acc[i][j][rr] + b1v[j]));
            }
        }
    }
    BAR();

    // ------------- layer 2: H[64x256] @ W2^T (zero-padded to 16) ----------
    const float* b2 = head ? pb2 : vb2;
    const int nOut = head ? 2 : 6;

    f32x4 acc2 = (f32x4){0.f, 0.f, 0.f, 0.f};
    const int tokb = wave * 16;
    const short* hbase  = (const short*)&H[(tokb + l16) * HSTR + quad * 8];
    const __hip_bfloat16* w2base = W2c + (head * 16 + l16) * HID + quad * 8;
    #pragma unroll
    for (int k0 = 0; k0 < HID; k0 += 32) {
        short8 af    = *(const short8*)(hbase + k0);
        short8 bfrag = *(const short8*)(w2base + k0);   // zero rows pad n>=nOut
        acc2 = __builtin_amdgcn_mfma_f32_16x16x32_bf16(af, bfrag, acc2, 0, 0, 0);
    }

    // ------------- masked epilogue (f32 writes) ---------------------------
    const float b2v = (l16 < nOut) ? b2[l16] : 0.0f;

    #pragma unroll
    for (int rr = 0; rr < 4; ++rr) {
        const int t = row0 + tokb + quad * 4 + rr;
        const int type = ids[t];
        if (head == 0) {
            if (l16 == 0) {
                out[TOKENS * 6 + t] = (type == 1) ? 1.0f : 0.0f;
                out[TOKENS * 7 + t] = (type == 2) ? 1.0f : 0.0f;
            }
            if (l16 < 6) {
                if (type == 1)
                    out[t * 6 + l16] = acc2[rr] + b2v;
                else if (type != 2)
                    out[t * 6 + l16] = 0.0f;        // types 0,3 -> zeros
                // type==2 slots written by the pedestrian block
            }
        } else {
            if (l16 < 6 && type == 2)
                out[t * 6 + l16] = (l16 < 2) ? (acc2[rr] + b2v) : 0.0f;
        }
    }
}

extern "C" void kernel_launch(void* const* d_in, const int* in_sizes, int n_in,
                              void* d_out, int out_size, void* d_ws, size_t ws_size,
                              hipStream_t stream) {
    (void)n_in; (void)out_size; (void)ws_size;
    const float* X   = (const float*)d_in[0];
    const int*   ids = (const int*)d_in[1];
    const float* vW1 = (const float*)d_in[2];
    const float* vb1 = (const float*)d_in[3];
    const float* vW2 = (const float*)d_in[4];
    const float* vb2 = (const float*)d_in[5];
    const float* pW1 = (const float*)d_in[6];
    const float* pb1 = (const float*)d_in[7];
    const float* pW2 = (const float*)d_in[8];
    const float* pb2 = (const float*)d_in[9];
    float* out = (float*)d_out;

    // workspace: Wc [512*512] bf16 (512KB) ++ W2c [32*256] bf16 (16KB)
    __hip_bfloat16* Wc  = (__hip_bfloat16*)d_ws;
    __hip_bfloat16* W2c = Wc + 512 * DIM;

    hipLaunchKernelGGL(prep_kernel, dim3(264), dim3(256), 0, stream,
                       vW1, pW1, vW2, pW2, Wc, W2c);

    const int tokens = in_sizes[1];            // 65536
    const int grid   = (tokens / 64) * 2;      // token-tile x head

    hipLaunchKernelGGL(intention_heads_kernel, dim3(grid), dim3(256), 0, stream,
                       X, ids, Wc, W2c, vb1, pb1, vb2, pb2, out);
}